// Round 1
// baseline (444.714 us; speedup 1.0000x reference)
//
#include <hip/hip_runtime.h>

// 5-level 3D Haar wavedec (db1, mode=zero, even sizes -> no padding).
// Input [4,8,128,128,128] fp32. Each level: thread t owns one half-res voxel,
// reads its 2x2x2 brick (4x float2, W-pairs are 8B aligned), does the
// separable butterfly, writes aaa + 7 detail subbands.
// aaa chain ping-pongs through d_ws; level-5 aaa = Yl goes to d_out[0].

#define C3 0.3535533905932738f  // (1/sqrt(2))^3

__global__ __launch_bounds__(256) void haar3_lvl(
    const float* __restrict__ in, float* __restrict__ out_a,
    float* __restrict__ out_d, long det_sz, int log2n, long total)
{
    long t = (long)blockIdx.x * 256 + threadIdx.x;
    if (t >= total) return;
    const int n  = 1 << log2n;
    const int m  = n - 1;
    const int wx = (int)(t & m);
    const int hy = (int)((t >> log2n) & m);
    const int dz = (int)((t >> (2 * log2n)) & m);
    const long b = t >> (3 * log2n);
    const long n2   = 2 * (long)n;
    const long rowD = n2 * n2;  // stride between D slices of the input
    const long base = ((b * n2 + 2 * dz) * n2 + 2 * hy) * n2 + 2 * wx;

    const float2 v00 = *(const float2*)(in + base);               // dd=0, dh=0
    const float2 v01 = *(const float2*)(in + base + n2);          // dd=0, dh=1
    const float2 v10 = *(const float2*)(in + base + rowD);        // dd=1, dh=0
    const float2 v11 = *(const float2*)(in + base + rowD + n2);   // dd=1, dh=1

    // W butterfly (lo = ev+od, hi = ev-od; scale folded into final C3)
    const float aw0 = v00.x + v00.y, dw0 = v00.x - v00.y;
    const float aw1 = v01.x + v01.y, dw1 = v01.x - v01.y;
    const float aw2 = v10.x + v10.y, dw2 = v10.x - v10.y;
    const float aw3 = v11.x + v11.y, dw3 = v11.x - v11.y;
    // H butterfly within each D slice
    const float aa0 = aw0 + aw1, da0 = aw0 - aw1, ad0 = dw0 + dw1, dd0 = dw0 - dw1;
    const float aa1 = aw2 + aw3, da1 = aw2 - aw3, ad1 = dw2 + dw3, dd1 = dw2 - dw3;
    // D butterfly -> 8 subbands; detail order must match KEYS:
    // aad, ada, add, daa, dad, dda, ddd  (letters = D,H,W axes)
    out_a[t]                = (aa0 + aa1) * C3;  // aaa
    out_d[t]                = (ad0 + ad1) * C3;  // aad
    out_d[t +     det_sz]   = (da0 + da1) * C3;  // ada
    out_d[t + 2 * det_sz]   = (dd0 + dd1) * C3;  // add
    out_d[t + 3 * det_sz]   = (aa0 - aa1) * C3;  // daa
    out_d[t + 4 * det_sz]   = (ad0 - ad1) * C3;  // dad
    out_d[t + 5 * det_sz]   = (da0 - da1) * C3;  // dda
    out_d[t + 6 * det_sz]   = (dd0 - dd1) * C3;  // ddd
}

extern "C" void kernel_launch(void* const* d_in, const int* in_sizes, int n_in,
                              void* d_out, int out_size, void* d_ws, size_t ws_size,
                              hipStream_t stream) {
    const float* x = (const float*)d_in[0];
    float* out  = (float*)d_out;
    float* buf0 = (float*)d_ws;              // 32*64^3 = 8,388,608 floats
    float* buf1 = buf0 + 8388608;            // 32*32^3 = 1,048,576 floats
    // ws usage: 9,437,184 floats = 36 MB

    // d_out layout (flat, fp32): Yl[2048] | L5 det 7x2048 | L4 det 7x16384 |
    // L3 det 7x131072 | L2 det 7x1048576 | L1 det 7x8388608
    struct Lv { const float* in; float* oa; float* od; int log2n; };
    const Lv lv[5] = {
        { x,    buf0, out + 8388608, 6 },  // L1: 128^3 -> 64^3
        { buf0, buf1, out + 1048576, 5 },  // L2: 64^3  -> 32^3
        { buf1, buf0, out + 131072,  4 },  // L3: 32^3  -> 16^3
        { buf0, buf1, out + 16384,   3 },  // L4: 16^3  -> 8^3
        { buf1, out,  out + 2048,    2 },  // L5: 8^3   -> 4^3, aaa -> Yl at offset 0
    };
    const long BC = 32;  // batch * channels
    for (int i = 0; i < 5; ++i) {
        const long total = BC << (3 * lv[i].log2n);
        const int blocks = (int)((total + 255) / 256);
        haar3_lvl<<<blocks, 256, 0, stream>>>(lv[i].in, lv[i].oa, lv[i].od,
                                              total, lv[i].log2n, total);
    }
}